// Round 1
// baseline (741.231 us; speedup 1.0000x reference)
//
#include <hip/hip_runtime.h>

// B=8, S=1024, H=128, all fp32.
// Two-pass:
//   K1: scores[b,i,j] = sum_h x[b,j,h]*rel[i,j,h]  -> d_ws fp32 [8][1024][1024] (32 MiB)
//   K2: per (b, 8 i-rows): softmax over j, then out[b,i,h] = sum_j w*x[b,j,h]
// rel (512 MB) streams from HBM exactly once (~81 us floor). x stays L2-hot
// (~1 GB total L2 traffic). Measured harness overhead (ws poison 338 us +
// d_in restore ~165 us) is included in dur_us and is not controllable here.

__device__ __forceinline__ float dot4(float4 a, float4 b) {
  return a.x * b.x + a.y * b.y + a.z * b.z + a.w * b.w;
}

__device__ __forceinline__ void fma4(float4& a, float s, float4 v) {
  a.x = fmaf(s, v.x, a.x);
  a.y = fmaf(s, v.y, a.y);
  a.z = fmaf(s, v.z, a.z);
  a.w = fmaf(s, v.w, a.w);
}

// ---------------------------------------------------------------------------
// K1: block = 256 threads = 16 j x 16 h-lanes; handles 8 i's, 16 j's, all 8 b.
// Thread (jj = t>>4, c = t&15): owns j, h-floats {4c..4c+3} u {64+4c..64+4c+3}.
// x fragments for all 8 b in 64 VGPRs, reused across the 8 i's.
// rel row double-buffered in registers (prefetch ii+1 before computing ii) so
// the HBM stream always has loads in flight. 3 blocks/CU (launch_bounds 256,3).
// ---------------------------------------------------------------------------
__global__ __launch_bounds__(256, 3)
void k_scores(const float* __restrict__ x, const float* __restrict__ rel,
              float* __restrict__ s_ws) {
  const int t  = threadIdx.x;
  const int c  = t & 15;
  const int jj = t >> 4;
  const int bx = blockIdx.x;
  const int it = bx & 127;   // i-tile fastest: consecutive blocks share the x j-tile in L2
  const int jt = bx >> 7;    // 64 j-tiles
  const int i0 = it << 3;
  const int j  = (jt << 4) + jj;

  // xr[b][k]: k=0 -> x[b][j][4c..4c+3], k=1 -> x[b][j][64+4c..64+4c+3]
  float4 xr[8][2];
#pragma unroll
  for (int b = 0; b < 8; ++b) {
    const float4* xp = (const float4*)(x + (((b << 10) + j) << 7));
    xr[b][0] = xp[c];
    xr[b][1] = xp[c + 16];
  }

  const float4* rbase = (const float4*)(rel + (((i0 << 10) + j) << 7));
  // i-row stride in float4s: 1024*128/4 = 32768
  float4 r0 = rbase[c];
  float4 r1 = rbase[c + 16];
#pragma unroll
  for (int ii = 0; ii < 8; ++ii) {
    float4 n0 = make_float4(0.f, 0.f, 0.f, 0.f);
    float4 n1 = n0;
    if (ii < 7) {  // compile-time under full unroll: prefetch next i-row
      const float4* rp = rbase + (ii + 1) * 32768;
      n0 = rp[c];
      n1 = rp[c + 16];
    }
    float s[8];
#pragma unroll
    for (int b = 0; b < 8; ++b) {
      float a = dot4(r0, xr[b][0]) + dot4(r1, xr[b][1]);
      // butterfly all-reduce over the 16 h-lanes (masks permute c only)
      a += __shfl_xor(a, 1);
      a += __shfl_xor(a, 2);
      a += __shfl_xor(a, 4);
      a += __shfl_xor(a, 8);
      s[b] = a;
    }
    if (c < 8) {  // lane c stores b = c
      float v = s[0];
#pragma unroll
      for (int b = 1; b < 8; ++b) v = (c == b) ? s[b] : v;
      s_ws[(c << 20) + ((i0 + ii) << 10) + j] = v;
    }
    r0 = n0;
    r1 = n1;
  }
}

// ---------------------------------------------------------------------------
// K2: block = 256 threads, one b and 8 i-rows (full j=1024). Unchanged logic
// from the passing round-1 kernel; occupancy raised to 4 blocks/CU.
// ---------------------------------------------------------------------------
__global__ __launch_bounds__(256, 4)
void k_softmax_av(const float* __restrict__ x, const float* __restrict__ s_ws,
                  float* __restrict__ out) {
  __shared__ float p_lds[8 * 1024];
  __shared__ float l_lds[8];
  const int t  = threadIdx.x;
  const int bx = blockIdx.x;
  const int b  = bx >> 7;
  const int i0 = (bx & 127) << 3;

  // --- step 1: load 8 contiguous score rows (8192 floats) into LDS
  {
    const float4* src = (const float4*)(s_ws + (((b << 10) + i0) << 10));
    float4* dst = (float4*)p_lds;
#pragma unroll
    for (int n = 0; n < 8; ++n) dst[t + (n << 8)] = src[t + (n << 8)];
  }
  __syncthreads();

  // --- step 2: softmax per row (unnormalized p; 1/l folded into epilogue)
  {
    const int r = t >> 5, c5 = t & 31;  // 32 threads per row
    float4 v[8];
    float m = -3.0e38f;
#pragma unroll
    for (int kk = 0; kk < 8; ++kk) {
      v[kk] = *(const float4*)&p_lds[(r << 10) + (c5 << 2) + (kk << 7)];
      m = fmaxf(m, fmaxf(fmaxf(v[kk].x, v[kk].y), fmaxf(v[kk].z, v[kk].w)));
    }
#pragma unroll
    for (int msk = 1; msk < 32; msk <<= 1) m = fmaxf(m, __shfl_xor(m, msk));
    float lsum = 0.f;
#pragma unroll
    for (int kk = 0; kk < 8; ++kk) {
      float4 e;
      e.x = __expf(v[kk].x - m);
      e.y = __expf(v[kk].y - m);
      e.z = __expf(v[kk].z - m);
      e.w = __expf(v[kk].w - m);
      lsum += (e.x + e.y) + (e.z + e.w);
      *(float4*)&p_lds[(r << 10) + (c5 << 2) + (kk << 7)] = e;
    }
#pragma unroll
    for (int msk = 1; msk < 32; msk <<= 1) lsum += __shfl_xor(lsum, msk);
    if (c5 == 0) l_lds[r] = lsum;
  }
  __syncthreads();

  // --- step 3: acc[i][4h] += p[i][j] * x[b][j][4h] over this thread's j-eighth
  const int hg = t & 31, js = t >> 5;
  float4 acc[8];
#pragma unroll
  for (int i = 0; i < 8; ++i) acc[i] = make_float4(0.f, 0.f, 0.f, 0.f);
  const int jbase = js << 7;
  const float* xb = x + (((b << 10) + jbase) << 7) + (hg << 2);
  for (int jj = 0; jj < 128; jj += 4) {
    const float4 x0 = *(const float4*)(xb + ((jj + 0) << 7));
    const float4 x1 = *(const float4*)(xb + ((jj + 1) << 7));
    const float4 x2 = *(const float4*)(xb + ((jj + 2) << 7));
    const float4 x3 = *(const float4*)(xb + ((jj + 3) << 7));
#pragma unroll
    for (int i = 0; i < 8; ++i) {
      const float4 p4 = *(const float4*)&p_lds[(i << 10) + jbase + jj];
      fma4(acc[i], p4.x, x0);
      fma4(acc[i], p4.y, x1);
      fma4(acc[i], p4.z, x2);
      fma4(acc[i], p4.w, x3);
    }
  }
  __syncthreads();  // all p reads done; reuse p_lds as reduce scratch

  // --- step 4: reduce 8 j-partials, scale by 1/l, store
#pragma unroll
  for (int i = 0; i < 8; ++i)
    *(float4*)&p_lds[((((js << 3) + i) << 5) + hg) << 2] = acc[i];
  __syncthreads();
  {
    const int hg2 = t & 31, ir = t >> 5;
    float4 sum = make_float4(0.f, 0.f, 0.f, 0.f);
#pragma unroll
    for (int p = 0; p < 8; ++p) {
      const float4 v = *(const float4*)&p_lds[((((p << 3) + ir) << 5) + hg2) << 2];
      sum.x += v.x; sum.y += v.y; sum.z += v.z; sum.w += v.w;
    }
    const float inv = 1.0f / l_lds[ir];
    const float4 o = make_float4(sum.x * inv, sum.y * inv, sum.z * inv, sum.w * inv);
    *(float4*)&out[(((b << 10) + i0 + ir) << 7) + (hg2 << 2)] = o;
  }
}

extern "C" void kernel_launch(void* const* d_in, const int* in_sizes, int n_in,
                              void* d_out, int out_size, void* d_ws, size_t ws_size,
                              hipStream_t stream) {
  const float* x   = (const float*)d_in[0];   // [8][1024][128] fp32
  const float* rel = (const float*)d_in[1];   // [1024][1024][128] fp32
  float* out  = (float*)d_out;                // [8][1024][128] fp32
  float* s_ws = (float*)d_ws;                 // scores [8][1024][1024] fp32 = 32 MiB

  k_scores<<<dim3(128 * 64), dim3(256), 0, stream>>>(x, rel, s_ws);
  k_softmax_av<<<dim3(8 * 128), dim3(256), 0, stream>>>(x, s_ws, out);
}

// Round 2
// 731.447 us; speedup vs baseline: 1.0134x; 1.0134x over previous
//
#include <hip/hip_runtime.h>

// B=8, S=1024, H=128, all fp32.
// Two-pass:
//   K1: scores[b,i,j] = sum_h x[b,j,h]*rel[i,j,h]  -> d_ws fp32 [8][1024][1024] (32 MiB)
//   K2: per (b, 8 i-rows): softmax over j, then out[b,i,h] = sum_j w*x[b,j,h]
// rel (512 MB) streams from HBM exactly once (~81 us floor). x stays L2-hot.
// Harness overhead (ws poison ~340 us + d_in restore ~165 us) is included in
// dur_us and is not controllable here. Controllable budget ~238 us.
//
// R1 changes (K1 only):
//  - 16-lane h-reduction moved from __shfl_xor (ds_swizzle, LDS pipe) to
//    VALU DPP row_ror adds: rows of 16 lanes == our c-groups exactly.
//  - rel prefetch depth 1 -> 2 (rotating 3-buffer, static %3 indices under
//    full unroll) so the consumed row was issued ~2 iters (~1100 cy) earlier.
//  - occupancy 3 -> 4 blocks/CU (est ~105 VGPR < 128 cap).
//  - rel loads nontemporal (read-once stream; keep x L2-resident).

typedef float f4v __attribute__((ext_vector_type(4)));

__device__ __forceinline__ float dot4v(f4v a, float4 b) {
  return a.x * b.x + a.y * b.y + a.z * b.z + a.w * b.w;
}

__device__ __forceinline__ void fma4(float4& a, float s, float4 v) {
  a.x = fmaf(s, v.x, a.x);
  a.y = fmaf(s, v.y, a.y);
  a.z = fmaf(s, v.z, a.z);
  a.w = fmaf(s, v.w, a.w);
}

// v + row_ror:N(v) on the VALU. DPP rows are 16 lanes: lanes {0..15} etc,
// which is exactly the c = t&15 reduction group. Summing rotations by
// 1,2,4,8 gives every lane the full 16-lane sum (ring butterfly).
template <int CTRL>
__device__ __forceinline__ float dpp_ror_add(float v) {
  int r = __builtin_amdgcn_update_dpp(0, __float_as_int(v), CTRL, 0xF, 0xF, true);
  return v + __int_as_float(r);
}

// ---------------------------------------------------------------------------
// K1: block = 256 threads = 16 j x 16 h-lanes; handles 8 i's, 16 j's, all 8 b.
// Thread (jj = t>>4, c = t&15): owns j, h-floats {4c..4c+3} u {64+4c..64+4c+3}.
// x fragments for all 8 b in 64 VGPRs, reused across the 8 i's.
// ---------------------------------------------------------------------------
__global__ __launch_bounds__(256, 4)
void k_scores(const float* __restrict__ x, const float* __restrict__ rel,
              float* __restrict__ s_ws) {
  const int t  = threadIdx.x;
  const int c  = t & 15;
  const int jj = t >> 4;
  const int bx = blockIdx.x;
  const int it = bx & 127;   // i-tile fastest: consecutive blocks share the x j-tile in L2
  const int jt = bx >> 7;    // 64 j-tiles
  const int i0 = it << 3;
  const int j  = (jt << 4) + jj;

  // xr[b][k]: k=0 -> x[b][j][4c..4c+3], k=1 -> x[b][j][64+4c..64+4c+3]
  float4 xr[8][2];
#pragma unroll
  for (int b = 0; b < 8; ++b) {
    const float4* xp = (const float4*)(x + (((b << 10) + j) << 7));
    xr[b][0] = xp[c];
    xr[b][1] = xp[c + 16];
  }

  const f4v* rbase = (const f4v*)(rel + (((i0 << 10) + j) << 7));
  // i-row stride in float4s: 1024*128/4 = 32768
  f4v rb[3][2];  // rotating prefetch buffers; all indices compile-time
  rb[0][0] = __builtin_nontemporal_load(rbase + c);
  rb[0][1] = __builtin_nontemporal_load(rbase + c + 16);
  rb[1][0] = __builtin_nontemporal_load(rbase + 32768 + c);
  rb[1][1] = __builtin_nontemporal_load(rbase + 32768 + c + 16);

#pragma unroll
  for (int ii = 0; ii < 8; ++ii) {
    if (ii < 6) {  // compile-time under full unroll: prefetch row ii+2
      const f4v* rp = rbase + (ii + 2) * 32768;
      rb[(ii + 2) % 3][0] = __builtin_nontemporal_load(rp + c);
      rb[(ii + 2) % 3][1] = __builtin_nontemporal_load(rp + c + 16);
    }
    const f4v r0 = rb[ii % 3][0];
    const f4v r1 = rb[ii % 3][1];
    float s[8];
#pragma unroll
    for (int b = 0; b < 8; ++b) {
      float a = dot4v(r0, xr[b][0]) + dot4v(r1, xr[b][1]);
      // 16-lane ring butterfly on VALU (DPP row_ror), no LDS pipe traffic
      a = dpp_ror_add<0x121>(a);  // row_ror:1
      a = dpp_ror_add<0x122>(a);  // row_ror:2
      a = dpp_ror_add<0x124>(a);  // row_ror:4
      a = dpp_ror_add<0x128>(a);  // row_ror:8
      s[b] = a;
    }
    if (c < 8) {  // lane c stores b = c
      float v = s[0];
#pragma unroll
      for (int b = 1; b < 8; ++b) v = (c == b) ? s[b] : v;
      s_ws[(c << 20) + ((i0 + ii) << 10) + j] = v;
    }
  }
}

// ---------------------------------------------------------------------------
// K2: block = 256 threads, one b and 8 i-rows (full j=1024). Unchanged.
// ---------------------------------------------------------------------------
__global__ __launch_bounds__(256, 4)
void k_softmax_av(const float* __restrict__ x, const float* __restrict__ s_ws,
                  float* __restrict__ out) {
  __shared__ float p_lds[8 * 1024];
  __shared__ float l_lds[8];
  const int t  = threadIdx.x;
  const int bx = blockIdx.x;
  const int b  = bx >> 7;
  const int i0 = (bx & 127) << 3;

  // --- step 1: load 8 contiguous score rows (8192 floats) into LDS
  {
    const float4* src = (const float4*)(s_ws + (((b << 10) + i0) << 10));
    float4* dst = (float4*)p_lds;
#pragma unroll
    for (int n = 0; n < 8; ++n) dst[t + (n << 8)] = src[t + (n << 8)];
  }
  __syncthreads();

  // --- step 2: softmax per row (unnormalized p; 1/l folded into epilogue)
  {
    const int r = t >> 5, c5 = t & 31;  // 32 threads per row
    float4 v[8];
    float m = -3.0e38f;
#pragma unroll
    for (int kk = 0; kk < 8; ++kk) {
      v[kk] = *(const float4*)&p_lds[(r << 10) + (c5 << 2) + (kk << 7)];
      m = fmaxf(m, fmaxf(fmaxf(v[kk].x, v[kk].y), fmaxf(v[kk].z, v[kk].w)));
    }
#pragma unroll
    for (int msk = 1; msk < 32; msk <<= 1) m = fmaxf(m, __shfl_xor(m, msk));
    float lsum = 0.f;
#pragma unroll
    for (int kk = 0; kk < 8; ++kk) {
      float4 e;
      e.x = __expf(v[kk].x - m);
      e.y = __expf(v[kk].y - m);
      e.z = __expf(v[kk].z - m);
      e.w = __expf(v[kk].w - m);
      lsum += (e.x + e.y) + (e.z + e.w);
      *(float4*)&p_lds[(r << 10) + (c5 << 2) + (kk << 7)] = e;
    }
#pragma unroll
    for (int msk = 1; msk < 32; msk <<= 1) lsum += __shfl_xor(lsum, msk);
    if (c5 == 0) l_lds[r] = lsum;
  }
  __syncthreads();

  // --- step 3: acc[i][4h] += p[i][j] * x[b][j][4h] over this thread's j-eighth
  const int hg = t & 31, js = t >> 5;
  float4 acc[8];
#pragma unroll
  for (int i = 0; i < 8; ++i) acc[i] = make_float4(0.f, 0.f, 0.f, 0.f);
  const int jbase = js << 7;
  const float* xb = x + (((b << 10) + jbase) << 7) + (hg << 2);
  for (int jj = 0; jj < 128; jj += 4) {
    const float4 x0 = *(const float4*)(xb + ((jj + 0) << 7));
    const float4 x1 = *(const float4*)(xb + ((jj + 1) << 7));
    const float4 x2 = *(const float4*)(xb + ((jj + 2) << 7));
    const float4 x3 = *(const float4*)(xb + ((jj + 3) << 7));
#pragma unroll
    for (int i = 0; i < 8; ++i) {
      const float4 p4 = *(const float4*)&p_lds[(i << 10) + jbase + jj];
      fma4(acc[i], p4.x, x0);
      fma4(acc[i], p4.y, x1);
      fma4(acc[i], p4.z, x2);
      fma4(acc[i], p4.w, x3);
    }
  }
  __syncthreads();  // all p reads done; reuse p_lds as reduce scratch

  // --- step 4: reduce 8 j-partials, scale by 1/l, store
#pragma unroll
  for (int i = 0; i < 8; ++i)
    *(float4*)&p_lds[((((js << 3) + i) << 5) + hg) << 2] = acc[i];
  __syncthreads();
  {
    const int hg2 = t & 31, ir = t >> 5;
    float4 sum = make_float4(0.f, 0.f, 0.f, 0.f);
#pragma unroll
    for (int p = 0; p < 8; ++p) {
      const float4 v = *(const float4*)&p_lds[((((p << 3) + ir) << 5) + hg2) << 2];
      sum.x += v.x; sum.y += v.y; sum.z += v.z; sum.w += v.w;
    }
    const float inv = 1.0f / l_lds[ir];
    const float4 o = make_float4(sum.x * inv, sum.y * inv, sum.z * inv, sum.w * inv);
    *(float4*)&out[(((b << 10) + i0 + ir) << 7) + (hg2 << 2)] = o;
  }
}

extern "C" void kernel_launch(void* const* d_in, const int* in_sizes, int n_in,
                              void* d_out, int out_size, void* d_ws, size_t ws_size,
                              hipStream_t stream) {
  const float* x   = (const float*)d_in[0];   // [8][1024][128] fp32
  const float* rel = (const float*)d_in[1];   // [1024][1024][128] fp32
  float* out  = (float*)d_out;                // [8][1024][128] fp32
  float* s_ws = (float*)d_ws;                 // scores [8][1024][1024] fp32 = 32 MiB

  k_scores<<<dim3(128 * 64), dim3(256), 0, stream>>>(x, rel, s_ws);
  k_softmax_av<<<dim3(8 * 128), dim3(256), 0, stream>>>(x, s_ws, out);
}